// Round 2
// baseline (115.199 us; speedup 1.0000x reference)
//
#include <hip/hip_runtime.h>
#include <hip/hip_bf16.h>

// Bloom MLP fused: h=X@W1^T+b1; g=gelu_tanh(h); out=g@W2^T+b2+residual
// X:[262144,64] f32, W1:[256,64], W2:[64,256], out:[262144,64] f32.
// bf16 MFMA (16x16x32), fp32 accumulate.
// Round 2: double-buffered LDS (parity) to kill cross-iteration WAR races;
// software prefetch of next X/R tile; grid 4096 x TILES 4.

typedef __attribute__((ext_vector_type(8))) short bf16x8;  // MFMA A/B frag (4 VGPR)
typedef __attribute__((ext_vector_type(4))) float f32x4;   // MFMA C/D frag

#define NTOK   262144
#define NBLK   4096
#define TILES  4        // 262144 / 16 rows / 4096 blocks

__device__ __forceinline__ short f2bf(float x) {
    union { float f; unsigned u; } v; v.f = x;
    unsigned r = v.u + 0x7FFFu + ((v.u >> 16) & 1u);   // RNE
    return (short)(r >> 16);
}

__device__ __forceinline__ float bloom_gelu(float x) {
    // 0.5*x*(1+tanh(0.79788456*(x+0.044715*x^3))), tanh(u)=1-2/(e^{2u}+1)
    float x3 = x * x * x;
    float u  = 0.79788456f * __builtin_fmaf(0.044715f, x3, x);
    float e  = __expf(2.0f * u);                        // v_exp path
    float t  = 1.0f - 2.0f * __builtin_amdgcn_rcpf(e + 1.0f);
    return 0.5f * x * (1.0f + t);
}

__global__ __launch_bounds__(256) void bloom_mlp(
    const float* __restrict__ X,  const float* __restrict__ R,
    const float* __restrict__ W1, const float* __restrict__ b1,
    const float* __restrict__ W2, const float* __restrict__ b2,
    float* __restrict__ out)
{
    // Double-buffered by iteration parity: writes at it+1 can never touch the
    // buffer being read at it. Padded rows (+8 shorts / +4 floats) break
    // power-of-2 bank strides.
    __shared__ __align__(16) short Gs[2][4][16][72];   // [par][wave][token][f_local]
    __shared__ __align__(16) float Ps[2][4][16][68];   // [par][wave][token][d]

    const int tid  = threadIdx.x;
    const int wid  = tid >> 6;     // wave 0..3 -> f-slice [64*wid, 64*wid+64)
    const int lane = tid & 63;
    const int q    = lane >> 4;    // 0..3
    const int c    = lane & 15;    // 0..15
    const int f0   = wid << 6;

    // epilogue mapping: 256 threads x 4 f32 = 16 tokens x 64 d
    const int m_r = tid >> 4;           // 0..15
    const int d0  = (tid & 15) << 2;    // 0,4,..,60

    // ---- prefetch helper: raw X (2 float4 per kblk) + residual for a tile ----
    auto issue_tile = [&](int it2, float4* xd, float4& rd) {
        const int row0 = (blockIdx.x * TILES + it2) << 4;
        const float* px = X + (size_t)(row0 + c) * 64 + q * 8;
        xd[0] = *(const float4*)(px);            // kb0 lo
        xd[1] = *(const float4*)(px + 4);        // kb0 hi
        xd[2] = *(const float4*)(px + 32);       // kb1 lo
        xd[3] = *(const float4*)(px + 36);       // kb1 hi
        rd    = *(const float4*)(R + (size_t)(row0 + m_r) * 64 + d0);
    };

    float4 curX[4]; float4 curR;
    issue_tile(0, curX, curR);     // in flight during weight preload

    // ---- preload weight B-fragments into registers (bf16), once per block ----
    bf16x8 w1f[4][2], w2f[4][2];
#pragma unroll
    for (int t = 0; t < 4; ++t)
#pragma unroll
        for (int kb = 0; kb < 2; ++kb) {
            const float* p = W1 + (size_t)(f0 + 16*t + c) * 64 + kb*32 + q*8;
            float4 lo = *(const float4*)p, hi = *(const float4*)(p + 4);
            bf16x8 f;
            f[0]=f2bf(lo.x); f[1]=f2bf(lo.y); f[2]=f2bf(lo.z); f[3]=f2bf(lo.w);
            f[4]=f2bf(hi.x); f[5]=f2bf(hi.y); f[6]=f2bf(hi.z); f[7]=f2bf(hi.w);
            w1f[t][kb] = f;
        }
#pragma unroll
    for (int dt = 0; dt < 4; ++dt)
#pragma unroll
        for (int kb = 0; kb < 2; ++kb) {
            const float* p = W2 + (size_t)(16*dt + c) * 256 + f0 + kb*32 + q*8;
            float4 lo = *(const float4*)p, hi = *(const float4*)(p + 4);
            bf16x8 f;
            f[0]=f2bf(lo.x); f[1]=f2bf(lo.y); f[2]=f2bf(lo.z); f[3]=f2bf(lo.w);
            f[4]=f2bf(hi.x); f[5]=f2bf(hi.y); f[6]=f2bf(hi.z); f[7]=f2bf(hi.w);
            w2f[dt][kb] = f;
        }

    float b1v[4];
#pragma unroll
    for (int t = 0; t < 4; ++t) b1v[t] = b1[f0 + 16*t + c];
    const float4 b2q = *(const float4*)(b2 + d0);

    for (int it = 0; it < TILES; ++it) {
        const int pb = it & 1;

        // ---- convert prefetched X to A-fragments ----
        bf16x8 a1[2];
#pragma unroll
        for (int kb = 0; kb < 2; ++kb) {
            float4 lo = curX[2*kb], hi = curX[2*kb + 1];
            bf16x8 f;
            f[0]=f2bf(lo.x); f[1]=f2bf(lo.y); f[2]=f2bf(lo.z); f[3]=f2bf(lo.w);
            f[4]=f2bf(hi.x); f[5]=f2bf(hi.y); f[6]=f2bf(hi.z); f[7]=f2bf(hi.w);
            a1[kb] = f;
        }

        // ---- GEMM1 + bias + GELU -> Gs[pb] (transpose via C-layout scatter) ----
        // C/D layout: lane holds D[4q+r][16t+c]  (row=token, col=f_local)
#pragma unroll
        for (int t = 0; t < 4; ++t) {
            f32x4 a = {0.f, 0.f, 0.f, 0.f};
            a = __builtin_amdgcn_mfma_f32_16x16x32_bf16(a1[0], w1f[t][0], a, 0, 0, 0);
            a = __builtin_amdgcn_mfma_f32_16x16x32_bf16(a1[1], w1f[t][1], a, 0, 0, 0);
#pragma unroll
            for (int r = 0; r < 4; ++r) {
                float h = a[r] + b1v[t];
                Gs[pb][wid][4*q + r][16*t + c] = f2bf(bloom_gelu(h));
            }
        }

        __syncthreads();  // Gs[pb] write -> read

        // ---- A-fragments for GEMM2 from Gs[pb] ----
        bf16x8 a2[2];
#pragma unroll
        for (int kb = 0; kb < 2; ++kb)
            a2[kb] = *(const bf16x8*)&Gs[pb][wid][c][kb*32 + q*8];

        // ---- prefetch next tile (in flight during GEMM2 + barrier + epilogue) ----
        float4 nxtX[4]; float4 nxtR;
        if (it + 1 < TILES) issue_tile(it + 1, nxtX, nxtR);

        // ---- GEMM2 partial over wave's f-slice -> Ps[pb] ----
#pragma unroll
        for (int dt = 0; dt < 4; ++dt) {
            f32x4 a = {0.f, 0.f, 0.f, 0.f};
            a = __builtin_amdgcn_mfma_f32_16x16x32_bf16(a2[0], w2f[dt][0], a, 0, 0, 0);
            a = __builtin_amdgcn_mfma_f32_16x16x32_bf16(a2[1], w2f[dt][1], a, 0, 0, 0);
#pragma unroll
            for (int r = 0; r < 4; ++r)
                Ps[pb][wid][4*q + r][16*dt + c] = a[r];
        }

        __syncthreads();  // Ps[pb] write -> reduce read

        // ---- cross-wave reduce + b2 + residual + store (float4 coalesced) ----
        {
            const int row0 = (blockIdx.x * TILES + it) << 4;
            const float4 s0 = *(const float4*)&Ps[pb][0][m_r][d0];
            const float4 s1 = *(const float4*)&Ps[pb][1][m_r][d0];
            const float4 s2 = *(const float4*)&Ps[pb][2][m_r][d0];
            const float4 s3 = *(const float4*)&Ps[pb][3][m_r][d0];
            float4 o;
            o.x = s0.x + s1.x + s2.x + s3.x + b2q.x + curR.x;
            o.y = s0.y + s1.y + s2.y + s3.y + b2q.y + curR.y;
            o.z = s0.z + s1.z + s2.z + s3.z + b2q.z + curR.z;
            o.w = s0.w + s1.w + s2.w + s3.w + b2q.w + curR.w;
            *(float4*)(out + (size_t)(row0 + m_r) * 64 + d0) = o;
        }

        if (it + 1 < TILES) {
#pragma unroll
            for (int i = 0; i < 4; ++i) curX[i] = nxtX[i];
            curR = nxtR;
        }
    }
}

extern "C" void kernel_launch(void* const* d_in, const int* in_sizes, int n_in,
                              void* d_out, int out_size, void* d_ws, size_t ws_size,
                              hipStream_t stream) {
    const float* X  = (const float*)d_in[0];
    const float* R  = (const float*)d_in[1];
    const float* W1 = (const float*)d_in[2];
    const float* b1 = (const float*)d_in[3];
    const float* W2 = (const float*)d_in[4];
    const float* b2 = (const float*)d_in[5];
    float* out = (float*)d_out;
    (void)in_sizes; (void)n_in; (void)out_size; (void)d_ws; (void)ws_size;
    bloom_mlp<<<NBLK, 256, 0, stream>>>(X, R, W1, b1, W2, b2, out);
}

// Round 3
// 97.325 us; speedup vs baseline: 1.1837x; 1.1837x over previous
//
#include <hip/hip_runtime.h>
#include <hip/hip_bf16.h>

// Bloom MLP fused: h=X@W1^T+b1; g=gelu_tanh(h); out=g@W2^T+b2+residual
// X:[262144,64] f32, W1:[256,64], W2:[64,256], out:[262144,64] f32.
//
// Round 3 structure: 64 tokens/block, grid 4096, NO loop, ONE barrier.
//  - GEMM1 (swapped operands): wave w computes f-slice [64w,64w+64) for all
//    64 tokens; D layout = [f_local=4q+r][token=c] -> 4 consecutive f per lane
//    -> GELU -> packed ds_write_b64 into G[token][f] LDS tile.
//  - GEMM2: wave w owns d-tile [16w,16w+16) over full K=256, A-frags from LDS
//    (ds_read_b128, 8 accesses/bank = optimal), accumulators -> registers ->
//    global store. No cross-wave reduce buffer.

typedef __attribute__((ext_vector_type(8))) short bf16x8;   // MFMA A/B frag
typedef __attribute__((ext_vector_type(4))) float f32x4;    // MFMA C/D frag
typedef __attribute__((ext_vector_type(4))) short short4v;  // packed 4x bf16

#define NBLK 4096   // 262144 tokens / 64 per block

__device__ __forceinline__ short f2bf(float x) {
    // let the compiler emit v_cvt_pk_bf16_f32 for pairs (m240)
    union { __hip_bfloat16 h; short s; } u;
    u.h = __float2bfloat16(x);
    return u.s;
}

__device__ __forceinline__ float bloom_gelu(float x) {
    // 0.5*x*(1+tanh(0.79788456*(x+0.044715*x^3)))
    //   = x * (1 - 1/(exp(2u)+1)),  2u = 1.59576912*x + 0.07135482*x^3
    float x2 = x * x;
    float t1 = __builtin_fmaf(0.07135482f, x2, 1.59576912f);
    float u2 = x * t1;
    float e  = __expf(u2);                       // inf/0 at extremes -> exact limits
    float r  = __builtin_amdgcn_rcpf(e + 1.0f);
    return x - x * r;
}

__global__ __launch_bounds__(256, 4) void bloom_mlp(
    const float* __restrict__ X,  const float* __restrict__ R,
    const float* __restrict__ W1, const float* __restrict__ b1,
    const float* __restrict__ W2, const float* __restrict__ b2,
    float* __restrict__ out)
{
    // G[token][f], bf16. Row stride 264 (528B = 33*16B): b64 writes hit
    // 4 accesses/bank, b128 reads 8/bank -- both the hardware minimum.
    __shared__ __align__(16) short Gs[64][264];

    const int tid  = threadIdx.x;
    const int wid  = tid >> 6;      // wave 0..3
    const int lane = tid & 63;
    const int q    = lane >> 4;     // 0..3
    const int c    = lane & 15;     // 0..15
    const int f0   = wid << 6;      // GEMM1 f-slice base
    const int row0 = blockIdx.x << 6;

    // ---- W1 fragments (A-operand): lane holds W1[f0+16t+c][kb*32+q*8 .. +7] ----
    bf16x8 w1f[4][2];
#pragma unroll
    for (int t = 0; t < 4; ++t)
#pragma unroll
        for (int kb = 0; kb < 2; ++kb) {
            const float* p = W1 + (size_t)(f0 + 16*t + c) * 64 + kb*32 + q*8;
            float4 lo = *(const float4*)p, hi = *(const float4*)(p + 4);
            bf16x8 f;
            f[0]=f2bf(lo.x); f[1]=f2bf(lo.y); f[2]=f2bf(lo.z); f[3]=f2bf(lo.w);
            f[4]=f2bf(hi.x); f[5]=f2bf(hi.y); f[6]=f2bf(hi.z); f[7]=f2bf(hi.w);
            w1f[t][kb] = f;
        }

    // b1 for this lane's 4 consecutive f per t: b1[f0+16t+4q .. +3]
    float4 b1q[4];
#pragma unroll
    for (int t = 0; t < 4; ++t)
        b1q[t] = *(const float4*)(b1 + f0 + 16*t + 4*q);

    // ---- GEMM1 + GELU -> Gs, per 16-token tile m ----
#pragma unroll
    for (int m = 0; m < 4; ++m) {
        // X fragments (B-operand): lane holds X[row0+16m+c][kb*32+q*8 .. +7]
        bf16x8 a1[2];
#pragma unroll
        for (int kb = 0; kb < 2; ++kb) {
            const float* p = X + (size_t)(row0 + 16*m + c) * 64 + kb*32 + q*8;
            float4 lo = *(const float4*)p, hi = *(const float4*)(p + 4);
            bf16x8 f;
            f[0]=f2bf(lo.x); f[1]=f2bf(lo.y); f[2]=f2bf(lo.z); f[3]=f2bf(lo.w);
            f[4]=f2bf(hi.x); f[5]=f2bf(hi.y); f[6]=f2bf(hi.z); f[7]=f2bf(hi.w);
            a1[kb] = f;
        }
        // D[f_local=4q+r][token=c] per f-tile t (swapped operands: W1 as A, X^T as B)
#pragma unroll
        for (int t = 0; t < 4; ++t) {
            f32x4 acc = {0.f, 0.f, 0.f, 0.f};
            acc = __builtin_amdgcn_mfma_f32_16x16x32_bf16(w1f[t][0], a1[0], acc, 0, 0, 0);
            acc = __builtin_amdgcn_mfma_f32_16x16x32_bf16(w1f[t][1], a1[1], acc, 0, 0, 0);
            short4v g;
#pragma unroll
            for (int r = 0; r < 4; ++r)
                g[r] = f2bf(bloom_gelu(acc[r] + b1q[t][r]));
            // token row = 16m+c, f cols = f0+16t+4q .. +3  (8B packed write)
            *(short4v*)&Gs[16*m + c][f0 + 16*t + 4*q] = g;
        }
    }

    // ---- W2 fragments (B-operand) for this wave's d-tile: issued before the
    //      barrier so the loads fly while other waves finish GEMM1 ----
    bf16x8 w2f[8];
#pragma unroll
    for (int kb = 0; kb < 8; ++kb) {
        const float* p = W2 + (size_t)(16*wid + c) * 256 + kb*32 + q*8;
        float4 lo = *(const float4*)p, hi = *(const float4*)(p + 4);
        bf16x8 f;
        f[0]=f2bf(lo.x); f[1]=f2bf(lo.y); f[2]=f2bf(lo.z); f[3]=f2bf(lo.w);
        f[4]=f2bf(hi.x); f[5]=f2bf(hi.y); f[6]=f2bf(hi.z); f[7]=f2bf(hi.w);
        w2f[kb] = f;
    }

    __syncthreads();   // the only barrier: G fully written -> readable by all

    // ---- GEMM2: wave w computes out[.., 16w..16w+16) over K=256 ----
    f32x4 acc2[4] = {{0.f,0.f,0.f,0.f},{0.f,0.f,0.f,0.f},
                     {0.f,0.f,0.f,0.f},{0.f,0.f,0.f,0.f}};
#pragma unroll
    for (int kb = 0; kb < 8; ++kb)
#pragma unroll
        for (int m = 0; m < 4; ++m) {
            bf16x8 a2 = *(const bf16x8*)&Gs[16*m + c][kb*32 + q*8];
            acc2[m] = __builtin_amdgcn_mfma_f32_16x16x32_bf16(a2, w2f[kb], acc2[m], 0, 0, 0);
        }

    // ---- epilogue: + b2 + residual, direct store (lane: D[4q+r][c]) ----
    const float b2c = b2[16*wid + c];
#pragma unroll
    for (int m = 0; m < 4; ++m)
#pragma unroll
        for (int r = 0; r < 4; ++r) {
            const size_t idx = (size_t)(row0 + 16*m + 4*q + r) * 64 + 16*wid + c;
            out[idx] = acc2[m][r] + b2c + R[idx];
        }
}

extern "C" void kernel_launch(void* const* d_in, const int* in_sizes, int n_in,
                              void* d_out, int out_size, void* d_ws, size_t ws_size,
                              hipStream_t stream) {
    const float* X  = (const float*)d_in[0];
    const float* R  = (const float*)d_in[1];
    const float* W1 = (const float*)d_in[2];
    const float* b1 = (const float*)d_in[3];
    const float* W2 = (const float*)d_in[4];
    const float* b2 = (const float*)d_in[5];
    float* out = (float*)d_out;
    (void)in_sizes; (void)n_in; (void)out_size; (void)d_ws; (void)ws_size;
    bloom_mlp<<<NBLK, 256, 0, stream>>>(X, R, W1, b1, W2, b2, out);
}

// Round 4
// 70.348 us; speedup vs baseline: 1.6376x; 1.3835x over previous
//
#include <hip/hip_runtime.h>
#include <hip/hip_bf16.h>

// Bloom MLP fused: h=X@W1^T+b1; g=gelu_tanh(h); out=g@W2^T+b2+residual
// X:[262144,64] f32, W1:[256,64], W2:[64,256], out:[262144,64] f32.
//
// Round 4:
//  - cvt_weights pre-kernel: W1,W2 -> bf16 in d_ws (64KB); main kernel loads
//    16B bf16 fragments directly (half the bytes, zero convert VALU).
//  - TILES=2, grid 2048: weight prologue amortized over 128 tokens.
//  - GEMM2 operands swapped: D[d_local][token] -> lane holds 4 consecutive d
//    -> float4 residual load + float4 out store.
//  - One barrier per tile (+1 between tiles for Gs WAR).

typedef __attribute__((ext_vector_type(8))) short bf16x8;   // MFMA A/B frag
typedef __attribute__((ext_vector_type(4))) float f32x4;    // MFMA C/D frag
typedef __attribute__((ext_vector_type(4))) short short4v;  // packed 4x bf16

#define NBLK  2048
#define TILES 2      // 2048 * 2 * 64 tokens = 262144

__device__ __forceinline__ short f2bf(float x) {
    union { __hip_bfloat16 h; short s; } u;
    u.h = __float2bfloat16(x);      // compiler pairs into v_cvt_pk_bf16_f32
    return u.s;
}

__device__ __forceinline__ float bloom_gelu(float x) {
    // 0.5*x*(1+tanh(0.79788456*(x+0.044715*x^3))) = x*(1 - 1/(e^{2u}+1))
    float x2 = x * x;
    float t1 = __builtin_fmaf(0.07135482f, x2, 1.59576912f);
    float e  = __expf(x * t1);
    float r  = __builtin_amdgcn_rcpf(e + 1.0f);
    return x - x * r;
}

// ---- pre-pass: convert W1 (16384 f32) then W2 (16384 f32) to bf16 in ws ----
__global__ __launch_bounds__(256) void cvt_weights(
    const float* __restrict__ W1, const float* __restrict__ W2,
    short* __restrict__ wsb)
{
    const int i4 = (blockIdx.x * 256 + threadIdx.x) * 4;   // 0..32764, step 4
    const float* src = (i4 < 16384) ? (W1 + i4) : (W2 + (i4 - 16384));
    float4 v = *(const float4*)src;
    short4v o;
    o[0] = f2bf(v.x); o[1] = f2bf(v.y); o[2] = f2bf(v.z); o[3] = f2bf(v.w);
    *(short4v*)(wsb + i4) = o;
}

template<bool PRE>
__global__ __launch_bounds__(256, 4) void bloom_mlp(
    const float* __restrict__ X,  const float* __restrict__ R,
    const float* __restrict__ W1, const float* __restrict__ b1,
    const float* __restrict__ W2, const float* __restrict__ b2,
    const short* __restrict__ Wb, float* __restrict__ out)
{
    // G[token][f] bf16, row stride 264 (528B): ds_write_b64 4 acc/bank,
    // ds_read_b128 8 acc/bank -- both the width minimum.
    __shared__ __align__(16) short Gs[64][264];

    const int tid  = threadIdx.x;
    const int wid  = tid >> 6;      // wave 0..3
    const int lane = tid & 63;
    const int q    = lane >> 4;     // 0..3
    const int c    = lane & 15;     // 0..15
    const int f0   = wid << 6;      // GEMM1 f-slice base

    // ---- weight fragments (register-resident across both tiles) ----
    bf16x8 w1f[4][2];   // GEMM1 A-op: lane holds W1[f0+16t+c][kb*32+q*8..+7]
    bf16x8 w2f[8];      // GEMM2 A-op: lane holds W2[16wid+c][kb*32+q*8..+7]
    if constexpr (PRE) {
        const short* W1b = Wb;
        const short* W2b = Wb + 16384;
#pragma unroll
        for (int t = 0; t < 4; ++t)
#pragma unroll
            for (int kb = 0; kb < 2; ++kb)
                w1f[t][kb] = *(const bf16x8*)&W1b[(f0 + 16*t + c) * 64 + kb*32 + q*8];
#pragma unroll
        for (int kb = 0; kb < 8; ++kb)
            w2f[kb] = *(const bf16x8*)&W2b[(16*wid + c) * 256 + kb*32 + q*8];
    } else {
#pragma unroll
        for (int t = 0; t < 4; ++t)
#pragma unroll
            for (int kb = 0; kb < 2; ++kb) {
                const float* p = W1 + (size_t)(f0 + 16*t + c) * 64 + kb*32 + q*8;
                float4 lo = *(const float4*)p, hi = *(const float4*)(p + 4);
                bf16x8 f;
                f[0]=f2bf(lo.x); f[1]=f2bf(lo.y); f[2]=f2bf(lo.z); f[3]=f2bf(lo.w);
                f[4]=f2bf(hi.x); f[5]=f2bf(hi.y); f[6]=f2bf(hi.z); f[7]=f2bf(hi.w);
                w1f[t][kb] = f;
            }
#pragma unroll
        for (int kb = 0; kb < 8; ++kb) {
            const float* p = W2 + (size_t)(16*wid + c) * 256 + kb*32 + q*8;
            float4 lo = *(const float4*)p, hi = *(const float4*)(p + 4);
            bf16x8 f;
            f[0]=f2bf(lo.x); f[1]=f2bf(lo.y); f[2]=f2bf(lo.z); f[3]=f2bf(lo.w);
            f[4]=f2bf(hi.x); f[5]=f2bf(hi.y); f[6]=f2bf(hi.z); f[7]=f2bf(hi.w);
            w2f[kb] = f;
        }
    }

    const float4 b2q = *(const float4*)(b2 + 16*wid + 4*q);

    for (int it = 0; it < TILES; ++it) {
        const int row0 = (blockIdx.x * TILES + it) << 6;

        // b1 for lane's 4 consecutive f per t (reloaded: short live range)
        float4 b1q[4];
#pragma unroll
        for (int t = 0; t < 4; ++t)
            b1q[t] = *(const float4*)(b1 + f0 + 16*t + 4*q);

        // ---- GEMM1 + GELU -> Gs ----
#pragma unroll
        for (int m = 0; m < 4; ++m) {
            bf16x8 a1[2];   // B-op: lane holds X[row0+16m+c][kb*32+q*8..+7]
#pragma unroll
            for (int kb = 0; kb < 2; ++kb) {
                const float* p = X + (size_t)(row0 + 16*m + c) * 64 + kb*32 + q*8;
                float4 lo = *(const float4*)p, hi = *(const float4*)(p + 4);
                bf16x8 f;
                f[0]=f2bf(lo.x); f[1]=f2bf(lo.y); f[2]=f2bf(lo.z); f[3]=f2bf(lo.w);
                f[4]=f2bf(hi.x); f[5]=f2bf(hi.y); f[6]=f2bf(hi.z); f[7]=f2bf(hi.w);
                a1[kb] = f;
            }
            // D[f_local=4q+r][token=c] per f-tile t
#pragma unroll
            for (int t = 0; t < 4; ++t) {
                f32x4 acc = {0.f, 0.f, 0.f, 0.f};
                acc = __builtin_amdgcn_mfma_f32_16x16x32_bf16(w1f[t][0], a1[0], acc, 0, 0, 0);
                acc = __builtin_amdgcn_mfma_f32_16x16x32_bf16(w1f[t][1], a1[1], acc, 0, 0, 0);
                short4v g;
#pragma unroll
                for (int r = 0; r < 4; ++r)
                    g[r] = f2bf(bloom_gelu(acc[r] + b1q[t][r]));
                *(short4v*)&Gs[16*m + c][f0 + 16*t + 4*q] = g;   // 8B packed
            }
        }

        // residual issued pre-barrier: lands during GEMM2
        float4 r4[4];
#pragma unroll
        for (int m = 0; m < 4; ++m)
            r4[m] = *(const float4*)(R + (size_t)(row0 + 16*m + c) * 64 + 16*wid + 4*q);

        __syncthreads();   // Gs fully written -> readable by all waves

        // ---- GEMM2: wave owns d-tile [16wid,16wid+16) over K=256 ----
        // swapped operands: D[d_local=4q+r][token=c] -> 4 consecutive d/lane
        f32x4 acc2[4] = {{0.f,0.f,0.f,0.f},{0.f,0.f,0.f,0.f},
                         {0.f,0.f,0.f,0.f},{0.f,0.f,0.f,0.f}};
#pragma unroll
        for (int kb = 0; kb < 8; ++kb)
#pragma unroll
            for (int m = 0; m < 4; ++m) {
                bf16x8 a2 = *(const bf16x8*)&Gs[16*m + c][kb*32 + q*8];
                acc2[m] = __builtin_amdgcn_mfma_f32_16x16x32_bf16(w2f[kb], a2, acc2[m], 0, 0, 0);
            }

        // ---- epilogue: float4 per (m): out[row0+16m+c][16wid+4q .. +3] ----
#pragma unroll
        for (int m = 0; m < 4; ++m) {
            float4 o;
            o.x = acc2[m][0] + b2q.x + r4[m].x;
            o.y = acc2[m][1] + b2q.y + r4[m].y;
            o.z = acc2[m][2] + b2q.z + r4[m].z;
            o.w = acc2[m][3] + b2q.w + r4[m].w;
            *(float4*)(out + (size_t)(row0 + 16*m + c) * 64 + 16*wid + 4*q) = o;
        }

        if (it + 1 < TILES) __syncthreads();   // Gs WAR across tiles
    }
}

extern "C" void kernel_launch(void* const* d_in, const int* in_sizes, int n_in,
                              void* d_out, int out_size, void* d_ws, size_t ws_size,
                              hipStream_t stream) {
    const float* X  = (const float*)d_in[0];
    const float* R  = (const float*)d_in[1];
    const float* W1 = (const float*)d_in[2];
    const float* b1 = (const float*)d_in[3];
    const float* W2 = (const float*)d_in[4];
    const float* b2 = (const float*)d_in[5];
    float* out = (float*)d_out;
    (void)in_sizes; (void)n_in; (void)out_size;

    if (ws_size >= 65536) {
        short* wsb = (short*)d_ws;
        cvt_weights<<<32, 256, 0, stream>>>(W1, W2, wsb);
        bloom_mlp<true><<<NBLK, 256, 0, stream>>>(X, R, W1, b1, W2, b2, wsb, out);
    } else {
        bloom_mlp<false><<<NBLK, 256, 0, stream>>>(X, R, W1, b1, W2, b2, nullptr, out);
    }
}